// Round 14
// baseline (375.389 us; speedup 1.0000x reference)
//
#include <hip/hip_runtime.h>

// LSTM B=2048, T=1024, H=50. Round 14: R13 + staggered B-reads (wave parity),
// XT register prefetch (k3 assembly off the critical path), wave-6 MFMA trim.
//
// grid=256 (1 block/CU), block=448 = 7 waves (1.75/SIMD), BW=8 batches.
// Wave w owns permuted gate-row tiles 2w, 2w+1 (rows n'=4j+g). Lane (kq,L15):
// pair (unit j = 8w + 4*(L15>>3) + kq, batch bl = L15&7); L15/L15+8 read the
// same hb row (free broadcast). A = scaled W' single f16 in VGPRs
// (i,f,o rows x -log2e; g rows x +2log2e -> exp2-only epilogue).
//   A K-slots: 0-49 W_hh | 50-55 zero (pad-unit h) | 56 wih_hi | 57 wih_hi |
//              58 wih_lo | 59 bias_hi | 60 bias_lo | 61-63 zero.
// kq==3 lanes rebuild the k=56..63 slice of B1 from XT[t][bl]={x_hi,x_lo}
// (prefetched one step ahead into a register). Odd waves read/consume B1
// before B0 (LDS completes in order -> their first MFMA starts in the first
// half of the burst). Wave 6's tile-13 chain (all-zero A) is skipped.
// Epilogue: fused 7-trans (R11). One barrier per step; loop unrolled x2.

#define H     50
#define TT    1024
#define BATCH 2048
#define BW    8
#define NTHR  448     // 7 waves
#define KP    80      // f16 per hb row (40-word stride, measured conflict-free)

typedef float        f32x4 __attribute__((ext_vector_type(4)));
typedef _Float16     f16x8 __attribute__((ext_vector_type(8)));
typedef unsigned int u32x4 __attribute__((ext_vector_type(4)));

__device__ __forceinline__ f16x8 fix_k3(u32x4 R, unsigned int xt, bool k3) {
    // kq==3 slice (k=56..63) = {x_hi, x_lo, x_hi, 1, 1, 0, 0, 0}
    u32x4 Bm;
    Bm[0] = k3 ? xt : R[0];
    Bm[1] = k3 ? ((xt & 0xFFFFu) | 0x3C000000u) : R[1];
    Bm[2] = k3 ? 0x00003C00u : R[2];
    Bm[3] = k3 ? 0u : R[3];
    return __builtin_bit_cast(f16x8, Bm);
}

__global__ __launch_bounds__(NTHR, 1) void lstm_kernel(
    const float* __restrict__ x,      // [B, T]
    const float* __restrict__ W_ih,   // [200]
    const float* __restrict__ W_hh,   // [200, 50]
    const float* __restrict__ b_ih,   // [200]
    const float* __restrict__ b_hh,   // [200]
    const float* __restrict__ W_lin,  // [50]
    const float* __restrict__ b_lin,  // [1]
    float* __restrict__ out)          // [B]
{
    __shared__ _Float16     hb[2][BW][KP];    // h^T, double-buffered
    __shared__ unsigned int XT[TT + 1][BW];   // packed {x_hi,x_lo}; row TT = 0
    __shared__ float        redH[H][BW];      // head reduction

    const int tid  = threadIdx.x;
    const int wave = tid >> 6;
    const int lane = tid & 63;
    const int L15  = lane & 15;
    const int kq   = lane >> 4;
    const int bl   = L15 & 7;
    const int b0   = blockIdx.x * BW;

    const int t0 = 2 * wave;                 // tiles t0, t0+1 (wave 6: 12,13)

    const float LOG2E  = 1.4426950408889634f;
    const float LOG2E2 = 2.8853900817779268f;

    // ---- A fragments: scaled permuted W' rows, single f16, in VGPRs ----
    f16x8 A[2][2];
    #pragma unroll
    for (int tt = 0; tt < 2; ++tt) {
        const int m  = (t0 + tt) * 16 + L15;
        const int jm = m >> 2, gm = m & 3;
        const bool v = (jm < H);
        const float s = (gm == 2) ? LOG2E2 : -LOG2E;
        float swih = 0.f, sbias = 0.f;
        if (v) {
            swih  = s * W_ih[gm * H + jm];
            sbias = s * (b_ih[gm * H + jm] + b_hh[gm * H + jm]);
        }
        const _Float16 whi = (_Float16)swih;
        const _Float16 wlo = (_Float16)(swih - (float)whi);
        const _Float16 bhi = (_Float16)sbias;
        const _Float16 blo = (_Float16)(sbias - (float)bhi);
        #pragma unroll
        for (int kf = 0; kf < 2; ++kf) {
            f16x8 vv;
            #pragma unroll
            for (int e = 0; e < 8; ++e) {
                const int k = kf * 32 + kq * 8 + e;
                _Float16 val = (_Float16)0.f;
                if (v) {
                    if (k < H)        val = (_Float16)(s * W_hh[(gm * H + jm) * H + k]);
                    else if (k == 56) val = whi;
                    else if (k == 57) val = whi;
                    else if (k == 58) val = wlo;
                    else if (k == 59) val = bhi;
                    else if (k == 60) val = blo;
                }
                vv[e] = val;
            }
            A[tt][kf] = vv;
        }
    }

    // ---- this lane's pair ----
    const int  j  = 8 * wave + ((L15 >> 3) << 2) + kq;   // 0..55 (50-55 pad)
    const bool jv = (j < H);
    const float wlin = jv ? W_lin[j] : 0.f;
    const bool k3 = (kq == 3);

    // ---- init: zero hb; fill XT (row TT zeroed for the prefetch tail) ----
    for (int i = tid; i < 2 * BW * KP; i += NTHR)
        ((_Float16*)hb)[i] = (_Float16)0.f;
    for (int i = tid; i < TT * BW; i += NTHR) {
        const int bb = i >> 10, t = i & 1023;
        const float xv = x[(size_t)(b0 + bb) * TT + t];
        const _Float16 xh = (_Float16)xv;
        const _Float16 xl = (_Float16)(xv - (float)xh);
        XT[t][bb] = (unsigned int)*(const unsigned short*)&xh |
                    ((unsigned int)*(const unsigned short*)&xl << 16);
    }
    if (tid < BW) XT[TT][tid] = 0u;

    float c = 0.f, hlast = 0.f;
    __syncthreads();

    unsigned int xt_cur = XT[0][bl];

    #pragma unroll 1
    for (int tbase = 0; tbase < TT; tbase += 2) {
        #pragma unroll
        for (int half = 0; half < 2; ++half) {
            const int t = tbase + half;
            const _Float16* hp = &hb[half][bl][0];        // cur buffer
            _Float16*       np = &hb[half ^ 1][bl][0];    // next buffer

            const f32x4 z = {0.f, 0.f, 0.f, 0.f};
            f32x4 a0, a1;
            if (wave == 6) {
                // tile 13 is all-zero A: single chain (a1 unused by real lanes)
                u32x4 R0 = *(const u32x4*)(hp + kq * 8);
                u32x4 R1 = *(const u32x4*)(hp + 32 + kq * 8);
                const f16x8 B0 = __builtin_bit_cast(f16x8, R0);
                a0 = __builtin_amdgcn_mfma_f32_16x16x32_f16(A[0][0], B0, z, 0, 0, 0);
                const f16x8 B1 = fix_k3(R1, xt_cur, k3);
                a0 = __builtin_amdgcn_mfma_f32_16x16x32_f16(A[0][1], B1, a0, 0, 0, 0);
                a1 = z;
            } else if (wave & 1) {
                // odd waves: B1 first (completes first -> earlier MFMA start)
                u32x4 R1 = *(const u32x4*)(hp + 32 + kq * 8);
                u32x4 R0 = *(const u32x4*)(hp + kq * 8);
                const f16x8 B1 = fix_k3(R1, xt_cur, k3);
                a0 = __builtin_amdgcn_mfma_f32_16x16x32_f16(A[0][1], B1, z, 0, 0, 0);
                a1 = __builtin_amdgcn_mfma_f32_16x16x32_f16(A[1][1], B1, z, 0, 0, 0);
                const f16x8 B0 = __builtin_bit_cast(f16x8, R0);
                a0 = __builtin_amdgcn_mfma_f32_16x16x32_f16(A[0][0], B0, a0, 0, 0, 0);
                a1 = __builtin_amdgcn_mfma_f32_16x16x32_f16(A[1][0], B0, a1, 0, 0, 0);
            } else {
                // even waves: B0 first
                u32x4 R0 = *(const u32x4*)(hp + kq * 8);
                u32x4 R1 = *(const u32x4*)(hp + 32 + kq * 8);
                const f16x8 B0 = __builtin_bit_cast(f16x8, R0);
                a0 = __builtin_amdgcn_mfma_f32_16x16x32_f16(A[0][0], B0, z, 0, 0, 0);
                a1 = __builtin_amdgcn_mfma_f32_16x16x32_f16(A[1][0], B0, z, 0, 0, 0);
                const f16x8 B1 = fix_k3(R1, xt_cur, k3);
                a0 = __builtin_amdgcn_mfma_f32_16x16x32_f16(A[0][1], B1, a0, 0, 0, 0);
                a1 = __builtin_amdgcn_mfma_f32_16x16x32_f16(A[1][1], B1, a1, 0, 0, 0);
            }

            // ---- prefetch next step's XT (latency hidden across barrier) ----
            const unsigned int xt_nxt = XT[t + 1][bl];

            // ---- select this lane's accumulator (tile t0 vs t0+1) ----
            const bool lo = (L15 < 8);
            const float gi = lo ? a0[0] : a1[0];
            const float gf = lo ? a0[1] : a1[1];
            const float gg = lo ? a0[2] : a1[2];
            const float go = lo ? a0[3] : a1[3];

            // ---- fused epilogue: 7 trans ----
            const float Ei = __builtin_amdgcn_exp2f(gi);
            const float Ef = __builtin_amdgcn_exp2f(gf);
            const float Eg = __builtin_amdgcn_exp2f(gg);
            const float Eo = __builtin_amdgcn_exp2f(go);
            const float P  = (1.0f + Ei) * (1.0f + Eg);
            const float Q  = 1.0f + Ef;
            const float num = __builtin_fmaf(c, P, (Eg - 1.0f) * Q);
            c = num * __builtin_amdgcn_rcpf(P * Q);
            const float ca = fminf(LOG2E2 * c, 80.0f);
            const float Ec = __builtin_amdgcn_exp2f(ca);
            const float h  = (Ec - 1.0f) *
                __builtin_amdgcn_rcpf((1.0f + Eo) * (1.0f + Ec));
            hlast = h;

            np[j] = (_Float16)h;   // unguarded: pad j -> zero-A slots 50-55
            xt_cur = xt_nxt;
            __syncthreads();
        }
    }

    // ---- head: out[b] = b_lin + sum_j W_lin[j] * h[j][b] ----
    if (jv) redH[j][bl] = wlin * hlast;
    __syncthreads();
    if (tid < BW) {
        float s = b_lin[0];
        #pragma unroll 10
        for (int jj = 0; jj < H; ++jj) s += redH[jj][tid];
        out[b0 + tid] = s;
    }
}

extern "C" void kernel_launch(void* const* d_in, const int* in_sizes, int n_in,
                              void* d_out, int out_size, void* d_ws, size_t ws_size,
                              hipStream_t stream) {
    const float* x     = (const float*)d_in[0];
    const float* W_ih  = (const float*)d_in[1];
    const float* W_hh  = (const float*)d_in[2];
    const float* b_ih  = (const float*)d_in[3];
    const float* b_hh  = (const float*)d_in[4];
    const float* W_lin = (const float*)d_in[5];
    const float* b_lin = (const float*)d_in[6];
    float* out = (float*)d_out;

    dim3 grid(BATCH / BW);    // 256 blocks, 1 per CU
    dim3 block(NTHR);         // 7 waves
    lstm_kernel<<<grid, block, 0, stream>>>(x, W_ih, W_hh, b_ih, b_hh,
                                            W_lin, b_lin, out);
}

// Round 15
// 348.717 us; speedup vs baseline: 1.0765x; 1.0765x over previous
//
#include <hip/hip_runtime.h>

// LSTM B=2048, T=1024, H=50. Round 15: exact R13 (champion, 344.9 us) +
// XT register prefetch (the single clean element of R14, isolated).
// R14's stagger + wave-branching regressed (-30 us): uniform code shape wins.
//
// grid=256 (1 block/CU), block=448 = 7 waves (1.75/SIMD), BW=8 batches.
// Wave w owns permuted gate-row tiles 2w, 2w+1 (rows n'=4j+g). Lane (kq,L15):
// pair (unit j = 8w + 4*(L15>>3) + kq, batch bl = L15&7); L15/L15+8 read the
// same hb row (free broadcast). A = scaled W' single f16 in VGPRs
// (i,f,o rows x -log2e; g rows x +2log2e -> exp2-only epilogue).
//   A K-slots: 0-49 W_hh | 50-55 zero (pad-unit h) | 56 wih_hi | 57 wih_hi |
//              58 wih_lo | 59 bias_hi | 60 bias_lo | 61-63 zero.
// kq==3 lanes rebuild the k=56..63 slice of B1 = {x_hi,x_lo,x_hi,1,1,0,0,0}
// from a REGISTER xt_cur (prefetched from XT[t+1][bl] the step before ->
// the ds_read_b32 leaves the post-barrier critical burst).
// Epilogue: fused 7-trans. One barrier per step; loop unrolled x2.

#define H     50
#define TT    1024
#define BATCH 2048
#define BW    8
#define NTHR  448     // 7 waves
#define KP    80      // f16 per hb row (40-word stride, measured conflict-free)

typedef float        f32x4 __attribute__((ext_vector_type(4)));
typedef _Float16     f16x8 __attribute__((ext_vector_type(8)));
typedef unsigned int u32x4 __attribute__((ext_vector_type(4)));

__global__ __launch_bounds__(NTHR, 1) void lstm_kernel(
    const float* __restrict__ x,      // [B, T]
    const float* __restrict__ W_ih,   // [200]
    const float* __restrict__ W_hh,   // [200, 50]
    const float* __restrict__ b_ih,   // [200]
    const float* __restrict__ b_hh,   // [200]
    const float* __restrict__ W_lin,  // [50]
    const float* __restrict__ b_lin,  // [1]
    float* __restrict__ out)          // [B]
{
    __shared__ _Float16     hb[2][BW][KP];    // h^T, double-buffered
    __shared__ unsigned int XT[TT + 1][BW];   // packed {x_hi,x_lo}; row TT = 0
    __shared__ float        redH[H][BW];      // head reduction

    const int tid  = threadIdx.x;
    const int wave = tid >> 6;
    const int lane = tid & 63;
    const int L15  = lane & 15;
    const int kq   = lane >> 4;
    const int bl   = L15 & 7;
    const int b0   = blockIdx.x * BW;

    const int t0 = 2 * wave;                 // tiles t0, t0+1 (wave 6: 12,13)

    const float LOG2E  = 1.4426950408889634f;
    const float LOG2E2 = 2.8853900817779268f;

    // ---- A fragments: scaled permuted W' rows, single f16, in VGPRs ----
    f16x8 A[2][2];
    #pragma unroll
    for (int tt = 0; tt < 2; ++tt) {
        const int m  = (t0 + tt) * 16 + L15;
        const int jm = m >> 2, gm = m & 3;
        const bool v = (jm < H);
        const float s = (gm == 2) ? LOG2E2 : -LOG2E;
        float swih = 0.f, sbias = 0.f;
        if (v) {
            swih  = s * W_ih[gm * H + jm];
            sbias = s * (b_ih[gm * H + jm] + b_hh[gm * H + jm]);
        }
        const _Float16 whi = (_Float16)swih;
        const _Float16 wlo = (_Float16)(swih - (float)whi);
        const _Float16 bhi = (_Float16)sbias;
        const _Float16 blo = (_Float16)(sbias - (float)bhi);
        #pragma unroll
        for (int kf = 0; kf < 2; ++kf) {
            f16x8 vv;
            #pragma unroll
            for (int e = 0; e < 8; ++e) {
                const int k = kf * 32 + kq * 8 + e;
                _Float16 val = (_Float16)0.f;
                if (v) {
                    if (k < H)        val = (_Float16)(s * W_hh[(gm * H + jm) * H + k]);
                    else if (k == 56) val = whi;
                    else if (k == 57) val = whi;
                    else if (k == 58) val = wlo;
                    else if (k == 59) val = bhi;
                    else if (k == 60) val = blo;
                }
                vv[e] = val;
            }
            A[tt][kf] = vv;
        }
    }

    // ---- this lane's pair ----
    const int  j  = 8 * wave + ((L15 >> 3) << 2) + kq;   // 0..55 (50-55 pad)
    const bool jv = (j < H);
    const float wlin = jv ? W_lin[j] : 0.f;
    const bool k3 = (kq == 3);

    // ---- init: zero hb; fill XT (row TT zeroed for the prefetch tail) ----
    for (int i = tid; i < 2 * BW * KP; i += NTHR)
        ((_Float16*)hb)[i] = (_Float16)0.f;
    for (int i = tid; i < TT * BW; i += NTHR) {
        const int bb = i >> 10, t = i & 1023;
        const float xv = x[(size_t)(b0 + bb) * TT + t];
        const _Float16 xh = (_Float16)xv;
        const _Float16 xl = (_Float16)(xv - (float)xh);
        XT[t][bb] = (unsigned int)*(const unsigned short*)&xh |
                    ((unsigned int)*(const unsigned short*)&xl << 16);
    }
    if (tid < BW) XT[TT][tid] = 0u;

    float c = 0.f, hlast = 0.f;
    __syncthreads();

    unsigned int xt_cur = XT[0][bl];

    #pragma unroll 1
    for (int tbase = 0; tbase < TT; tbase += 2) {
        #pragma unroll
        for (int half = 0; half < 2; ++half) {
            const int t = tbase + half;
            const _Float16* hp = &hb[half][bl][0];        // cur buffer
            _Float16*       np = &hb[half ^ 1][bl][0];    // next buffer

            // ---- B fragments (uniform order, identical for all waves) ----
            f16x8 B0 = *(const f16x8*)(hp + kq * 8);      // k 0..31
            u32x4 Bh = *(const u32x4*)(hp + 32 + kq * 8); // k 32..63 (as u32)
            // kq==3 lanes: slice = {xh, xl, xh, 1, 1, 0, 0, 0} from register
            u32x4 Bm;
            Bm[0] = k3 ? xt_cur : Bh[0];
            Bm[1] = k3 ? ((xt_cur & 0xFFFFu) | 0x3C000000u) : Bh[1];
            Bm[2] = k3 ? 0x00003C00u : Bh[2];
            Bm[3] = k3 ? 0u : Bh[3];
            const f16x8 B1 = __builtin_bit_cast(f16x8, Bm);

            // ---- 4 MFMAs: two independent 2-deep chains ----
            const f32x4 z = {0.f, 0.f, 0.f, 0.f};
            f32x4 a0 = __builtin_amdgcn_mfma_f32_16x16x32_f16(A[0][0], B0, z, 0, 0, 0);
            f32x4 a1 = __builtin_amdgcn_mfma_f32_16x16x32_f16(A[1][0], B0, z, 0, 0, 0);
            a0 = __builtin_amdgcn_mfma_f32_16x16x32_f16(A[0][1], B1, a0, 0, 0, 0);
            a1 = __builtin_amdgcn_mfma_f32_16x16x32_f16(A[1][1], B1, a1, 0, 0, 0);

            // ---- prefetch next step's XT (off the critical burst) ----
            const unsigned int xt_nxt = XT[t + 1][bl];

            // ---- select this lane's accumulator (tile t0 vs t0+1) ----
            const bool lo = (L15 < 8);
            const float gi = lo ? a0[0] : a1[0];
            const float gf = lo ? a0[1] : a1[1];
            const float gg = lo ? a0[2] : a1[2];
            const float go = lo ? a0[3] : a1[3];

            // ---- fused epilogue: 7 trans ----
            const float Ei = __builtin_amdgcn_exp2f(gi);
            const float Ef = __builtin_amdgcn_exp2f(gf);
            const float Eg = __builtin_amdgcn_exp2f(gg);
            const float Eo = __builtin_amdgcn_exp2f(go);
            const float P  = (1.0f + Ei) * (1.0f + Eg);
            const float Q  = 1.0f + Ef;
            const float num = __builtin_fmaf(c, P, (Eg - 1.0f) * Q);
            c = num * __builtin_amdgcn_rcpf(P * Q);
            const float ca = fminf(LOG2E2 * c, 80.0f);
            const float Ec = __builtin_amdgcn_exp2f(ca);
            const float h  = (Ec - 1.0f) *
                __builtin_amdgcn_rcpf((1.0f + Eo) * (1.0f + Ec));
            hlast = h;

            np[j] = (_Float16)h;   // unguarded: pad j -> zero-A slots 50-55
            xt_cur = xt_nxt;
            __syncthreads();
        }
    }

    // ---- head: out[b] = b_lin + sum_j W_lin[j] * h[j][b] ----
    if (jv) redH[j][bl] = wlin * hlast;
    __syncthreads();
    if (tid < BW) {
        float s = b_lin[0];
        #pragma unroll 10
        for (int jj = 0; jj < H; ++jj) s += redH[jj][tid];
        out[b0 + tid] = s;
    }
}

extern "C" void kernel_launch(void* const* d_in, const int* in_sizes, int n_in,
                              void* d_out, int out_size, void* d_ws, size_t ws_size,
                              hipStream_t stream) {
    const float* x     = (const float*)d_in[0];
    const float* W_ih  = (const float*)d_in[1];
    const float* W_hh  = (const float*)d_in[2];
    const float* b_ih  = (const float*)d_in[3];
    const float* b_hh  = (const float*)d_in[4];
    const float* W_lin = (const float*)d_in[5];
    const float* b_lin = (const float*)d_in[6];
    float* out = (float*)d_out;

    dim3 grid(BATCH / BW);    // 256 blocks, 1 per CU
    dim3 block(NTHR);         // 7 waves
    lstm_kernel<<<grid, block, 0, stream>>>(x, W_ih, W_hh, b_ih, b_hh,
                                            W_lin, b_lin, out);
}